// Round 1
// baseline (683.217 us; speedup 1.0000x reference)
//
#include <hip/hip_runtime.h>

#define NB 4
#define NC 256
#define ND 46
#define NH 55
#define NW 46
#define NN (ND*NH*NW)      // 116380
#define NR 200
#define NL 201             // labels 0..200 (0 = background)
#define NVEC (NN/4)        // 29095, NN divisible by 4
#define NCHUNKS 16
#define PLANES_PER_WAVE 4
#define PLANES_PER_BLOCK 16  // 4 waves * 4 planes

// ---------------- counts: histogram of atlas labels ----------------
__global__ __launch_bounds__(256) void roi_count(const int* __restrict__ atlas,
                                                 float* __restrict__ counts) {
    __shared__ float h[NL];
    const int tid = threadIdx.x;
    for (int i = tid; i < NL; i += 256) h[i] = 0.0f;
    __syncthreads();

    const int iv = blockIdx.x * 256 + tid;
    if (iv < NVEC) {
        int4 lab = ((const int4*)atlas)[iv];
        atomicAdd(&h[lab.x], 1.0f);
        atomicAdd(&h[lab.y], 1.0f);
        atomicAdd(&h[lab.z], 1.0f);
        atomicAdd(&h[lab.w], 1.0f);
    }
    __syncthreads();
    for (int i = tid; i < NL; i += 256) {
        float v = h[i];
        if (i > 0 && v != 0.0f) atomicAdd(&counts[i - 1], v);
    }
}

// ---------------- main accumulation ----------------
// grid.x = NCHUNKS (n-chunks), grid.y = 64 (plane groups of 16)
// block = 256 threads = 4 waves; each wave owns 4 consecutive planes.
__global__ __launch_bounds__(256) void roi_accum(const float* __restrict__ fm,
                                                 const int* __restrict__ atlas,
                                                 float* __restrict__ sums) {
    __shared__ float bins[PLANES_PER_BLOCK][NL];
    const int tid = threadIdx.x;
    for (int i = tid; i < PLANES_PER_BLOCK * NL; i += 256)
        (&bins[0][0])[i] = 0.0f;
    __syncthreads();

    const int wave = tid >> 6;
    const int lane = tid & 63;
    const int plane0 = blockIdx.y * PLANES_PER_BLOCK + wave * PLANES_PER_WAVE;
    const int w4 = wave * PLANES_PER_WAVE;

    const int chunkv = (NVEC + NCHUNKS - 1) / NCHUNKS;
    const int v0 = blockIdx.x * chunkv;
    const int v1 = min(NVEC, v0 + chunkv);

    const int4*   atlas4 = (const int4*)atlas;
    const float4* f0 = (const float4*)(fm + (size_t)(plane0 + 0) * NN);
    const float4* f1 = (const float4*)(fm + (size_t)(plane0 + 1) * NN);
    const float4* f2 = (const float4*)(fm + (size_t)(plane0 + 2) * NN);
    const float4* f3 = (const float4*)(fm + (size_t)(plane0 + 3) * NN);

    for (int iv = v0 + lane; iv < v1; iv += 64) {
        int4   lab = atlas4[iv];
        float4 a = f0[iv];
        float4 b = f1[iv];
        float4 c = f2[iv];
        float4 d = f3[iv];
        // component x
        atomicAdd(&bins[w4 + 0][lab.x], a.x);
        atomicAdd(&bins[w4 + 1][lab.x], b.x);
        atomicAdd(&bins[w4 + 2][lab.x], c.x);
        atomicAdd(&bins[w4 + 3][lab.x], d.x);
        // component y
        atomicAdd(&bins[w4 + 0][lab.y], a.y);
        atomicAdd(&bins[w4 + 1][lab.y], b.y);
        atomicAdd(&bins[w4 + 2][lab.y], c.y);
        atomicAdd(&bins[w4 + 3][lab.y], d.y);
        // component z
        atomicAdd(&bins[w4 + 0][lab.z], a.z);
        atomicAdd(&bins[w4 + 1][lab.z], b.z);
        atomicAdd(&bins[w4 + 2][lab.z], c.z);
        atomicAdd(&bins[w4 + 3][lab.z], d.z);
        // component w
        atomicAdd(&bins[w4 + 0][lab.w], a.w);
        atomicAdd(&bins[w4 + 1][lab.w], b.w);
        atomicAdd(&bins[w4 + 2][lab.w], c.w);
        atomicAdd(&bins[w4 + 3][lab.w], d.w);
    }
    __syncthreads();

    // flush: skip background bin (label 0)
    for (int i = tid; i < PLANES_PER_BLOCK * NR; i += 256) {
        const int pp = i / NR;       // plane within block
        const int r  = i % NR;       // roi index 0..199 (label r+1)
        const float v = bins[pp][r + 1];
        if (v != 0.0f) {
            const int plane = blockIdx.y * PLANES_PER_BLOCK + pp;
            const int b = plane >> 8;      // / NC
            const int c = plane & 255;     // % NC
            atomicAdd(&sums[((size_t)b * NR + r) * NC + c], v);
        }
    }
}

// ---------------- finalize: divide + mask ----------------
__global__ __launch_bounds__(256) void roi_final(float* __restrict__ out,
                                                 const float* __restrict__ counts) {
    const int i = blockIdx.x * 256 + threadIdx.x;
    const int nfeat = NB * NR * NC;
    if (i < nfeat) {
        const int r = (i / NC) % NR;
        const float cnt = counts[r];
        out[i] = (cnt > 0.0f) ? out[i] / cnt : 0.0f;
    } else if (i < nfeat + NB * NR) {
        const int j = i - nfeat;
        const int r = j % NR;
        out[i] = (counts[r] > 0.0f) ? 1.0f : 0.0f;
    }
}

extern "C" void kernel_launch(void* const* d_in, const int* in_sizes, int n_in,
                              void* d_out, int out_size, void* d_ws, size_t ws_size,
                              hipStream_t stream) {
    const float* fm    = (const float*)d_in[0];
    const int*   atlas = (const int*)d_in[1];
    float*       out   = (float*)d_out;
    float*       counts = (float*)d_ws;   // 200 floats

    // zero accumulators (sums live in d_out's roi_features region)
    hipMemsetAsync(out, 0, (size_t)NB * NR * NC * sizeof(float), stream);
    hipMemsetAsync(counts, 0, NR * sizeof(float), stream);

    roi_count<<<(NVEC + 255) / 256, 256, 0, stream>>>(atlas, counts);
    roi_accum<<<dim3(NCHUNKS, (NB * NC) / PLANES_PER_BLOCK), 256, 0, stream>>>(fm, atlas, out);

    const int total = NB * NR * NC + NB * NR;
    roi_final<<<(total + 255) / 256, 256, 0, stream>>>(out, counts);
}

// Round 2
// 611.484 us; speedup vs baseline: 1.1173x; 1.1173x over previous
//
#include <hip/hip_runtime.h>

#define NB 4
#define NC 256
#define ND 46
#define NH 55
#define NW 46
#define NN (ND*NH*NW)      // 116380
#define NR 200
#define NL 201             // labels 0..200 (0 = background)
#define NVEC (NN/4)        // 29095 (NN divisible by 4)
#define NPLANES (NB*NC)    // 1024
#define NCHUNK 8
#define PPB 4              // planes per block
#define NFEAT (NB*NR*NC)   // 204800

// ---------------- counts: histogram of atlas labels ----------------
__global__ __launch_bounds__(256) void roi_count(const int* __restrict__ atlas,
                                                 float* __restrict__ counts) {
    __shared__ float h[NL];
    const int tid = threadIdx.x;
    for (int i = tid; i < NL; i += 256) h[i] = 0.0f;
    __syncthreads();

    const int iv = blockIdx.x * 256 + tid;
    if (iv < NVEC) {
        int4 lab = ((const int4*)atlas)[iv];
        atomicAdd(&h[lab.x], 1.0f);
        atomicAdd(&h[lab.y], 1.0f);
        atomicAdd(&h[lab.z], 1.0f);
        atomicAdd(&h[lab.w], 1.0f);
    }
    __syncthreads();
    for (int i = tid; i < NL; i += 256) {
        float v = h[i];
        if (i > 0 && v != 0.0f) atomicAdd(&counts[i - 1], v);
    }
}

// ---------------- main accumulation ----------------
// grid = (NCHUNK, NPLANES/PPB) = (8, 256) = 2048 blocks; 256 thr = 4 waves.
// All threads of a block work the same 4 planes over one n-chunk.
__global__ __launch_bounds__(256) void roi_accum(const float* __restrict__ fm,
                                                 const int* __restrict__ atlas,
                                                 float* __restrict__ dst,
                                                 const int use_ws) {
    __shared__ float bins[PPB][NL];
    const int tid = threadIdx.x;
    for (int i = tid; i < PPB * NL; i += 256) (&bins[0][0])[i] = 0.0f;
    __syncthreads();

    const int plane0 = blockIdx.y * PPB;
    const int chunkv = (NVEC + NCHUNK - 1) / NCHUNK;   // 3637
    const int v0 = blockIdx.x * chunkv;
    const int v1 = min(NVEC, v0 + chunkv);

    const int4*   atlas4 = (const int4*)atlas;
    const float4* f0 = (const float4*)(fm + (size_t)(plane0 + 0) * NN);
    const float4* f1 = (const float4*)(fm + (size_t)(plane0 + 1) * NN);
    const float4* f2 = (const float4*)(fm + (size_t)(plane0 + 2) * NN);
    const float4* f3 = (const float4*)(fm + (size_t)(plane0 + 3) * NN);

    for (int iv = v0 + tid; iv < v1; iv += 256) {
        int4   lab = atlas4[iv];
        float4 a = f0[iv];
        float4 b = f1[iv];
        float4 c = f2[iv];
        float4 d = f3[iv];
        atomicAdd(&bins[0][lab.x], a.x);
        atomicAdd(&bins[1][lab.x], b.x);
        atomicAdd(&bins[2][lab.x], c.x);
        atomicAdd(&bins[3][lab.x], d.x);

        atomicAdd(&bins[0][lab.y], a.y);
        atomicAdd(&bins[1][lab.y], b.y);
        atomicAdd(&bins[2][lab.y], c.y);
        atomicAdd(&bins[3][lab.y], d.y);

        atomicAdd(&bins[0][lab.z], a.z);
        atomicAdd(&bins[1][lab.z], b.z);
        atomicAdd(&bins[2][lab.z], c.z);
        atomicAdd(&bins[3][lab.z], d.z);

        atomicAdd(&bins[0][lab.w], a.w);
        atomicAdd(&bins[1][lab.w], b.w);
        atomicAdd(&bins[2][lab.w], c.w);
        atomicAdd(&bins[3][lab.w], d.w);
    }
    __syncthreads();

    if (use_ws) {
        // private slice: partials[(chunk*NPLANES + plane0)*NR + i], i = pp*NR + r
        float* base = dst + ((size_t)blockIdx.x * NPLANES + plane0) * NR;
        for (int i = tid; i < PPB * NR; i += 256)
            base[i] = bins[i / NR][i % NR + 1];
    } else {
        for (int i = tid; i < PPB * NR; i += 256) {
            const float v = bins[i / NR][i % NR + 1];
            if (v != 0.0f) {
                const int plane = plane0 + i / NR;
                const int r = i % NR;
                const int b = plane >> 8;
                const int c = plane & 255;
                atomicAdd(&dst[((size_t)b * NR + r) * NC + c], v);
            }
        }
    }
}

// ---------------- finalize (ws path): reduce partials + divide + mask ----------------
__global__ __launch_bounds__(256) void roi_final_ws(const float* __restrict__ partials,
                                                    const float* __restrict__ counts,
                                                    float* __restrict__ out) {
    const int j = blockIdx.x * 256 + threadIdx.x;
    if (j < NFEAT) {
        // j = plane*NR + r  -> coalesced partials reads
        float s = 0.0f;
        #pragma unroll
        for (int ch = 0; ch < NCHUNK; ++ch)
            s += partials[(size_t)ch * NFEAT + j];
        const int plane = j / NR;
        const int r = j % NR;
        const int b = plane >> 8;
        const int c = plane & 255;
        const float cnt = counts[r];
        out[((size_t)b * NR + r) * NC + c] = (cnt > 0.0f) ? s / cnt : 0.0f;
    } else if (j < NFEAT + NB * NR) {
        const int j2 = j - NFEAT;
        const int r = j2 % NR;
        out[NFEAT + j2] = (counts[r] > 0.0f) ? 1.0f : 0.0f;
    }
}

// ---------------- finalize (atomic fallback): divide in place + mask ----------------
__global__ __launch_bounds__(256) void roi_final(float* __restrict__ out,
                                                 const float* __restrict__ counts) {
    const int i = blockIdx.x * 256 + threadIdx.x;
    if (i < NFEAT) {
        const int r = (i / NC) % NR;
        const float cnt = counts[r];
        out[i] = (cnt > 0.0f) ? out[i] / cnt : 0.0f;
    } else if (i < NFEAT + NB * NR) {
        const int r = (i - NFEAT) % NR;
        out[i] = (counts[r] > 0.0f) ? 1.0f : 0.0f;
    }
}

extern "C" void kernel_launch(void* const* d_in, const int* in_sizes, int n_in,
                              void* d_out, int out_size, void* d_ws, size_t ws_size,
                              hipStream_t stream) {
    const float* fm    = (const float*)d_in[0];
    const int*   atlas = (const int*)d_in[1];
    float*       out   = (float*)d_out;

    float* counts   = (float*)d_ws;        // 256-float slot (uses 200)
    float* partials = counts + 256;        // NCHUNK * NPLANES * NR floats

    const size_t need = (size_t)(256 + (size_t)NCHUNK * NPLANES * NR) * sizeof(float);
    const int use_ws = (ws_size >= need) ? 1 : 0;

    hipMemsetAsync(counts, 0, NR * sizeof(float), stream);
    if (!use_ws)
        hipMemsetAsync(out, 0, (size_t)NFEAT * sizeof(float), stream);

    roi_count<<<(NVEC + 255) / 256, 256, 0, stream>>>(atlas, counts);

    roi_accum<<<dim3(NCHUNK, NPLANES / PPB), 256, 0, stream>>>(
        fm, atlas, use_ws ? partials : out, use_ws);

    const int total = NFEAT + NB * NR;
    if (use_ws)
        roi_final_ws<<<(total + 255) / 256, 256, 0, stream>>>(partials, counts, out);
    else
        roi_final<<<(total + 255) / 256, 256, 0, stream>>>(out, counts);
}

// Round 3
// 326.260 us; speedup vs baseline: 2.0941x; 1.8742x over previous
//
#include <hip/hip_runtime.h>

#define NB 4
#define NC 256
#define ND 46
#define NH 55
#define NW 46
#define NN (ND*NH*NW)        // 116380
#define NVEC (NN/4)          // 29095
#define NR 200
#define NL 201
#define NPLANES (NB*NC)      // 1024
#define NFEAT (NB*NR*NC)     // 204800
#define KCH 16               // k-split chunks
#define SP 228               // k-steps (of 32 voxels) per chunk: 16*228 >= 3637
#define TOTFULL 3636         // full 32-voxel steps; step 3636 is partial (28)
#define MROI 256             // padded roi rows (labels compared 1..256; >200 never match)

typedef __attribute__((ext_vector_type(8))) short bf16x8;
typedef __attribute__((ext_vector_type(4))) float f32x4;

__device__ __forceinline__ unsigned short f2bf(float x) {
    unsigned u = __float_as_uint(x);
    unsigned r = u + 0x7FFFu + ((u >> 16) & 1u);   // RNE to bf16
    return (unsigned short)(r >> 16);
}
__device__ __forceinline__ unsigned pkf(float x, float y) {
    return (unsigned)f2bf(x) | ((unsigned)f2bf(y) << 16);
}
__device__ __forceinline__ unsigned oneif(int l, int c) {
    return (l == c) ? 0x3F80u : 0u;   // bf16 1.0
}
__device__ __forceinline__ bf16x8 pack4(unsigned a, unsigned b, unsigned c, unsigned d) {
    union { unsigned u[4]; bf16x8 v; } x;
    x.u[0] = a; x.u[1] = b; x.u[2] = c; x.u[3] = d;
    return x.v;
}
__device__ __forceinline__ bf16x8 mkA(const int4& la, const int4& lb, int c) {
    return pack4(oneif(la.x, c) | (oneif(la.y, c) << 16),
                 oneif(la.z, c) | (oneif(la.w, c) << 16),
                 oneif(lb.x, c) | (oneif(lb.y, c) << 16),
                 oneif(lb.z, c) | (oneif(lb.w, c) << 16));
}

// ---------------- counts: histogram of atlas labels ----------------
__global__ __launch_bounds__(256) void roi_count(const int* __restrict__ atlas,
                                                 float* __restrict__ counts) {
    __shared__ float h[NL];
    const int tid = threadIdx.x;
    for (int i = tid; i < NL; i += 256) h[i] = 0.0f;
    __syncthreads();
    const int iv = blockIdx.x * 256 + tid;
    if (iv < NVEC) {
        int4 lab = ((const int4*)atlas)[iv];
        atomicAdd(&h[lab.x], 1.0f);
        atomicAdd(&h[lab.y], 1.0f);
        atomicAdd(&h[lab.z], 1.0f);
        atomicAdd(&h[lab.w], 1.0f);
    }
    __syncthreads();
    for (int i = tid; i < NL; i += 256) {
        float v = h[i];
        if (i > 0 && v != 0.0f) atomicAdd(&counts[i - 1], v);
    }
}

// ---------------- main: one-hot MFMA GEMM ----------------
// grid = (KCH, NPLANES/16); block = 256 (4 waves).
// Block C-tile: 256 roi-rows x 16 planes over its k-chunk.
// Wave w owns roi-tiles 4w..4w+3 (16 rois each). MFMA 16x16x32 bf16.
__global__ __launch_bounds__(256) void roi_accum_mfma(const float* __restrict__ fm,
                                                      const int* __restrict__ atlas,
                                                      float* __restrict__ partials) {
    const int tid  = threadIdx.x;
    const int wave = tid >> 6;
    const int lane = tid & 63;
    const int g    = lane >> 4;      // k-group 0..3
    const int n    = lane & 15;      // plane-in-tile (B/D col) & roi row (A)
    const int pb    = blockIdx.y * 16;
    const int plane = pb + n;
    const int chunk = blockIdx.x;

    const float4* f4     = (const float4*)(fm + (size_t)plane * NN);
    const int4*   atlas4 = (const int4*)atlas;

    f32x4 acc0 = {0.f,0.f,0.f,0.f};
    f32x4 acc1 = {0.f,0.f,0.f,0.f};
    f32x4 acc2 = {0.f,0.f,0.f,0.f};
    f32x4 acc3 = {0.f,0.f,0.f,0.f};

    const int t0 = wave * 4;
    const int c0 = (t0 + 0) * 16 + n + 1;   // label values to match
    const int c1 = (t0 + 1) * 16 + n + 1;
    const int c2 = (t0 + 2) * 16 + n + 1;
    const int c3 = (t0 + 3) * 16 + n + 1;

    const int s0 = chunk * SP;
    const int s1 = min(s0 + SP, TOTFULL);

    #pragma unroll 2
    for (int s = s0; s < s1; ++s) {
        const int i4 = s * 8 + 2 * g;
        int4   la = atlas4[i4];
        int4   lb = atlas4[i4 + 1];
        float4 fa = f4[i4];
        float4 fb = f4[i4 + 1];
        bf16x8 B = pack4(pkf(fa.x, fa.y), pkf(fa.z, fa.w),
                         pkf(fb.x, fb.y), pkf(fb.z, fb.w));
        acc0 = __builtin_amdgcn_mfma_f32_16x16x32_bf16(mkA(la, lb, c0), B, acc0, 0, 0, 0);
        acc1 = __builtin_amdgcn_mfma_f32_16x16x32_bf16(mkA(la, lb, c1), B, acc1, 0, 0, 0);
        acc2 = __builtin_amdgcn_mfma_f32_16x16x32_bf16(mkA(la, lb, c2), B, acc2, 0, 0, 0);
        acc3 = __builtin_amdgcn_mfma_f32_16x16x32_bf16(mkA(la, lb, c3), B, acc3, 0, 0, 0);
    }

    // partial tail step (voxels 116352..116379; 28 valid)
    if (s0 <= TOTFULL && TOTFULL < s0 + SP) {
        const int i4 = TOTFULL * 8 + 2 * g;
        const int4   zi = {0, 0, 0, 0};
        const float4 zf = {0.f, 0.f, 0.f, 0.f};
        int4   la = atlas4[i4];                                  // always in range
        int4   lb = (i4 + 1 < NVEC) ? atlas4[i4 + 1] : zi;       // g==3 OOB
        float4 fa = f4[i4];
        float4 fb = (i4 + 1 < NVEC) ? f4[i4 + 1] : zf;
        bf16x8 B = pack4(pkf(fa.x, fa.y), pkf(fa.z, fa.w),
                         pkf(fb.x, fb.y), pkf(fb.z, fb.w));
        acc0 = __builtin_amdgcn_mfma_f32_16x16x32_bf16(mkA(la, lb, c0), B, acc0, 0, 0, 0);
        acc1 = __builtin_amdgcn_mfma_f32_16x16x32_bf16(mkA(la, lb, c1), B, acc1, 0, 0, 0);
        acc2 = __builtin_amdgcn_mfma_f32_16x16x32_bf16(mkA(la, lb, c2), B, acc2, 0, 0, 0);
        acc3 = __builtin_amdgcn_mfma_f32_16x16x32_bf16(mkA(la, lb, c3), B, acc3, 0, 0, 0);
    }

    // store: partials[chunk][roi (256)][plane (1024)]
    // D layout: col = lane&15 (plane), row = 4*(lane>>4)+i (roi within tile)
    float* pc = partials + (size_t)chunk * (MROI * NPLANES);
    const int rbase = 4 * g;
    #pragma unroll
    for (int i = 0; i < 4; ++i) {
        pc[(size_t)((t0 + 0) * 16 + rbase + i) * NPLANES + plane] = acc0[i];
        pc[(size_t)((t0 + 1) * 16 + rbase + i) * NPLANES + plane] = acc1[i];
        pc[(size_t)((t0 + 2) * 16 + rbase + i) * NPLANES + plane] = acc2[i];
        pc[(size_t)((t0 + 3) * 16 + rbase + i) * NPLANES + plane] = acc3[i];
    }
}

// ---------------- finalize: reduce chunks + divide + mask ----------------
__global__ __launch_bounds__(256) void roi_final2(const float* __restrict__ partials,
                                                  const float* __restrict__ counts,
                                                  float* __restrict__ out) {
    const int j = blockIdx.x * 256 + threadIdx.x;
    if (j < NFEAT) {
        const int c = j & (NC - 1);
        const int r = (j >> 8) % NR;
        const int b = j / (NR * NC);
        const int plane = b * NC + c;
        float s = 0.0f;
        #pragma unroll
        for (int ch = 0; ch < KCH; ++ch)
            s += partials[((size_t)ch * MROI + r) * NPLANES + plane];
        const float cnt = counts[r];
        out[j] = (cnt > 0.0f) ? s / cnt : 0.0f;
    } else if (j < NFEAT + NB * NR) {
        const int r = (j - NFEAT) % NR;
        out[j] = (counts[r] > 0.0f) ? 1.0f : 0.0f;
    }
}

extern "C" void kernel_launch(void* const* d_in, const int* in_sizes, int n_in,
                              void* d_out, int out_size, void* d_ws, size_t ws_size,
                              hipStream_t stream) {
    const float* fm    = (const float*)d_in[0];
    const int*   atlas = (const int*)d_in[1];
    float*       out   = (float*)d_out;

    float* counts   = (float*)d_ws;     // 256 floats
    float* partials = counts + 256;     // KCH * MROI * NPLANES floats (16.78 MB)

    hipMemsetAsync(counts, 0, NR * sizeof(float), stream);

    roi_count<<<(NVEC + 255) / 256, 256, 0, stream>>>(atlas, counts);

    roi_accum_mfma<<<dim3(KCH, NPLANES / 16), 256, 0, stream>>>(fm, atlas, partials);

    const int total = NFEAT + NB * NR;
    roi_final2<<<(total + 255) / 256, 256, 0, stream>>>(partials, counts, out);
}

// Round 4
// 248.984 us; speedup vs baseline: 2.7440x; 1.3104x over previous
//
#include <hip/hip_runtime.h>

#define NB 4
#define NC 256
#define ND 46
#define NH 55
#define NW 46
#define NN (ND*NH*NW)        // 116380
#define NVEC (NN/4)          // 29095
#define NR 200
#define NL 201
#define NPLANES (NB*NC)      // 1024
#define NFEAT (NB*NR*NC)     // 204800
#define TOTSTEPS 3637        // 32-voxel k-steps (last partial: 28)
#define TOTFULL 3636
#define MROI 256             // padded roi rows

typedef __attribute__((ext_vector_type(8))) short bf16x8;
typedef __attribute__((ext_vector_type(4))) float f32x4;

__device__ __forceinline__ bf16x8 pack4u(unsigned a, unsigned b, unsigned c, unsigned d) {
    union { unsigned u[4]; bf16x8 v; } x;
    x.u[0] = a; x.u[1] = b; x.u[2] = c; x.u[3] = d;
    return x.v;
}
// two f32 -> packed bf16 pair (round-half-up, 2 add + 1 v_perm)
__device__ __forceinline__ unsigned pkbf(float x, float y) {
    unsigned ux = __float_as_uint(x) + 0x8000u;
    unsigned uy = __float_as_uint(y) + 0x8000u;
    return __builtin_amdgcn_perm(uy, ux, 0x07060302u);  // lo16=hi(ux), hi16=hi(uy)
}
__device__ __forceinline__ bf16x8 mkB(const float4& a, const float4& b) {
    return pack4u(pkbf(a.x, a.y), pkbf(a.z, a.w), pkbf(b.x, b.y), pkbf(b.z, b.w));
}
// packed one-hot pair: lo match -> 0x3F80 (bf16 1.0), hi match -> 0x3F800000
__device__ __forceinline__ unsigned oh2(int l0, int l1, int c) {
    return (l0 == c ? 0x3F80u : 0u) | (l1 == c ? 0x3F800000u : 0u);
}
__device__ __forceinline__ bf16x8 mkA(const int4& la, const int4& lb, int c) {
    return pack4u(oh2(la.x, la.y, c), oh2(la.z, la.w, c),
                  oh2(lb.x, lb.y, c), oh2(lb.z, lb.w, c));
}

// ---------------- counts: histogram of atlas labels ----------------
__global__ __launch_bounds__(256) void roi_count(const int* __restrict__ atlas,
                                                 float* __restrict__ counts) {
    __shared__ float h[NL];
    const int tid = threadIdx.x;
    for (int i = tid; i < NL; i += 256) h[i] = 0.0f;
    __syncthreads();
    const int iv = blockIdx.x * 256 + tid;
    if (iv < NVEC) {
        int4 lab = ((const int4*)atlas)[iv];
        atomicAdd(&h[lab.x], 1.0f);
        atomicAdd(&h[lab.y], 1.0f);
        atomicAdd(&h[lab.z], 1.0f);
        atomicAdd(&h[lab.w], 1.0f);
    }
    __syncthreads();
    for (int i = tid; i < NL; i += 256) {
        float v = h[i];
        if (i > 0 && v != 0.0f) atomicAdd(&counts[i - 1], v);
    }
}

// ---------------- main: one-hot MFMA GEMM, 2 plane-tiles per wave ----------------
// grid = (KCH, NPLANES/32); block = 256 (4 waves).
// Block C-tile: 256 rois x 32 planes. Wave w: rois 64w..64w+63 (4 roi-tiles),
// both plane-tiles (A-fragments reused across 2 B's).
__global__ __launch_bounds__(256, 4) void roi_accum_mfma2(const float* __restrict__ fm,
                                                          const int* __restrict__ atlas,
                                                          float* __restrict__ partials,
                                                          const int SPl) {
    const int tid  = threadIdx.x;
    const int wave = tid >> 6;
    const int lane = tid & 63;
    const int g    = lane >> 4;       // k-group 0..3
    const int n    = lane & 15;       // col within tile / row within roi-tile
    const int pb   = blockIdx.y * 32;
    const int chunk = blockIdx.x;

    const float4* fA = (const float4*)(fm + (size_t)(pb + n) * NN);
    const float4* fB = (const float4*)(fm + (size_t)(pb + 16 + n) * NN);
    const int4*   atlas4 = (const int4*)atlas;

    f32x4 acc[4][2];
    #pragma unroll
    for (int t = 0; t < 4; ++t)
        #pragma unroll
        for (int p = 0; p < 2; ++p)
            acc[t][p] = (f32x4){0.f, 0.f, 0.f, 0.f};

    const int t0 = wave * 4;
    const int cbase = t0 * 16 + n + 1;     // label for roi-tile t: cbase + 16t

    const int s0 = chunk * SPl;
    const int send = min(s0 + SPl, TOTFULL);

    for (int s = s0; s < send; ++s) {
        const int i4 = s * 8 + 2 * g;
        int4   la = atlas4[i4];
        int4   lb = atlas4[i4 + 1];
        float4 a0 = fA[i4];
        float4 b0 = fA[i4 + 1];
        float4 a1 = fB[i4];
        float4 b1 = fB[i4 + 1];
        bf16x8 B0 = mkB(a0, b0);
        bf16x8 B1 = mkB(a1, b1);
        #pragma unroll
        for (int t = 0; t < 4; ++t) {
            bf16x8 A = mkA(la, lb, cbase + 16 * t);
            acc[t][0] = __builtin_amdgcn_mfma_f32_16x16x32_bf16(A, B0, acc[t][0], 0, 0, 0);
            acc[t][1] = __builtin_amdgcn_mfma_f32_16x16x32_bf16(A, B1, acc[t][1], 0, 0, 0);
        }
    }

    // tail step (28 valid voxels): g==3's second int4/float4 is OOB
    if (s0 <= TOTFULL && TOTFULL < s0 + SPl) {
        const int i4 = TOTFULL * 8 + 2 * g;
        const int4   zi = {0, 0, 0, 0};
        const float4 zf = {0.f, 0.f, 0.f, 0.f};
        const bool ok = (i4 + 1 < NVEC);
        int4   la = atlas4[i4];
        int4   lb = ok ? atlas4[i4 + 1] : zi;
        float4 a0 = fA[i4];
        float4 b0 = ok ? fA[i4 + 1] : zf;
        float4 a1 = fB[i4];
        float4 b1 = ok ? fB[i4 + 1] : zf;
        bf16x8 B0 = mkB(a0, b0);
        bf16x8 B1 = mkB(a1, b1);
        #pragma unroll
        for (int t = 0; t < 4; ++t) {
            bf16x8 A = mkA(la, lb, cbase + 16 * t);
            acc[t][0] = __builtin_amdgcn_mfma_f32_16x16x32_bf16(A, B0, acc[t][0], 0, 0, 0);
            acc[t][1] = __builtin_amdgcn_mfma_f32_16x16x32_bf16(A, B1, acc[t][1], 0, 0, 0);
        }
    }

    // store: partials[chunk][roi(256)][plane(1024)]
    // D layout: col = lane&15, row = 4*(lane>>4)+i
    float* pc = partials + (size_t)chunk * (MROI * NPLANES);
    const int rbase = 4 * g;
    #pragma unroll
    for (int t = 0; t < 4; ++t)
        #pragma unroll
        for (int p = 0; p < 2; ++p)
            #pragma unroll
            for (int i = 0; i < 4; ++i)
                pc[(size_t)((t0 + t) * 16 + rbase + i) * NPLANES + (pb + 16 * p + n)] = acc[t][p][i];
}

// ---------------- finalize: reduce chunks + divide + mask ----------------
__global__ __launch_bounds__(256) void roi_final2(const float* __restrict__ partials,
                                                  const float* __restrict__ counts,
                                                  float* __restrict__ out,
                                                  const int kch) {
    const int j = blockIdx.x * 256 + threadIdx.x;
    if (j < NFEAT) {
        const int c = j & (NC - 1);
        const int r = (j >> 8) % NR;
        const int b = j / (NR * NC);
        const int plane = b * NC + c;
        float s = 0.0f;
        for (int ch = 0; ch < kch; ++ch)
            s += partials[((size_t)ch * MROI + r) * NPLANES + plane];
        const float cnt = counts[r];
        out[j] = (cnt > 0.0f) ? s / cnt : 0.0f;
    } else if (j < NFEAT + NB * NR) {
        const int r = (j - NFEAT) % NR;
        out[j] = (counts[r] > 0.0f) ? 1.0f : 0.0f;
    }
}

extern "C" void kernel_launch(void* const* d_in, const int* in_sizes, int n_in,
                              void* d_out, int out_size, void* d_ws, size_t ws_size,
                              hipStream_t stream) {
    const float* fm    = (const float*)d_in[0];
    const int*   atlas = (const int*)d_in[1];
    float*       out   = (float*)d_out;

    float* counts   = (float*)d_ws;     // 256 floats
    float* partials = counts + 256;     // kch * MROI * NPLANES floats

    int kch = 32;
    if (ws_size < (size_t)(256 + (size_t)32 * MROI * NPLANES) * sizeof(float))
        kch = 16;
    const int spl = (TOTSTEPS + kch - 1) / kch;

    hipMemsetAsync(counts, 0, NR * sizeof(float), stream);

    roi_count<<<(NVEC + 255) / 256, 256, 0, stream>>>(atlas, counts);

    roi_accum_mfma2<<<dim3(kch, NPLANES / 32), 256, 0, stream>>>(fm, atlas, partials, spl);

    const int total = NFEAT + NB * NR;
    roi_final2<<<(total + 255) / 256, 256, 0, stream>>>(partials, counts, out, kch);
}

// Round 5
// 248.209 us; speedup vs baseline: 2.7526x; 1.0031x over previous
//
#include <hip/hip_runtime.h>

#define NB 4
#define NC 256
#define ND 46
#define NH 55
#define NW 46
#define NN (ND*NH*NW)        // 116380
#define NVEC (NN/4)          // 29095
#define NR 200
#define NL 201
#define NPLANES (NB*NC)      // 1024
#define NFEAT (NB*NR*NC)     // 204800
#define TOTSTEPS 3637        // 32-voxel k-steps (last partial: 28)
#define TOTFULL 3636
#define MROI 256             // padded roi rows

typedef __attribute__((ext_vector_type(8))) short bf16x8;
typedef __attribute__((ext_vector_type(4))) float f32x4;

__device__ __forceinline__ bf16x8 pack4u(unsigned a, unsigned b, unsigned c, unsigned d) {
    union { unsigned u[4]; bf16x8 v; } x;
    x.u[0] = a; x.u[1] = b; x.u[2] = c; x.u[3] = d;
    return x.v;
}
// two f32 -> packed bf16 pair (round-half-up, 2 add + 1 v_perm)
__device__ __forceinline__ unsigned pkbf(float x, float y) {
    unsigned ux = __float_as_uint(x) + 0x8000u;
    unsigned uy = __float_as_uint(y) + 0x8000u;
    return __builtin_amdgcn_perm(uy, ux, 0x07060302u);  // lo16=hi(ux), hi16=hi(uy)
}
__device__ __forceinline__ bf16x8 mkB(const float4& a, const float4& b) {
    return pack4u(pkbf(a.x, a.y), pkbf(a.z, a.w), pkbf(b.x, b.y), pkbf(b.z, b.w));
}
// packed one-hot pair: lo match -> 0x3F80 (bf16 1.0), hi match -> 0x3F800000
__device__ __forceinline__ unsigned oh2(int l0, int l1, int c) {
    return (l0 == c ? 0x3F80u : 0u) | (l1 == c ? 0x3F800000u : 0u);
}
__device__ __forceinline__ bf16x8 mkA(const int4& la, const int4& lb, int c) {
    return pack4u(oh2(la.x, la.y, c), oh2(la.z, la.w, c),
                  oh2(lb.x, lb.y, c), oh2(lb.z, lb.w, c));
}

// ---------------- counts: histogram of atlas labels ----------------
__global__ __launch_bounds__(256) void roi_count(const int* __restrict__ atlas,
                                                 float* __restrict__ counts) {
    __shared__ float h[NL];
    const int tid = threadIdx.x;
    for (int i = tid; i < NL; i += 256) h[i] = 0.0f;
    __syncthreads();
    const int iv = blockIdx.x * 256 + tid;
    if (iv < NVEC) {
        int4 lab = ((const int4*)atlas)[iv];
        atomicAdd(&h[lab.x], 1.0f);
        atomicAdd(&h[lab.y], 1.0f);
        atomicAdd(&h[lab.z], 1.0f);
        atomicAdd(&h[lab.w], 1.0f);
    }
    __syncthreads();
    for (int i = tid; i < NL; i += 256) {
        float v = h[i];
        if (i > 0 && v != 0.0f) atomicAdd(&counts[i - 1], v);
    }
}

// ---------------- main: one-hot MFMA GEMM, wave tile 64 rois x 64 planes ----------
// grid = (KCH, NPLANES/64 = 16); block = 256 (4 waves).
// Block C-tile: 256 rois x 64 planes. Wave w: rois 64w..64w+63 (4 roi-tiles),
// all 4 plane-tiles. A-fragments amortized over 4 B's.
__global__ __launch_bounds__(256, 4) void roi_accum_mfma4(const float* __restrict__ fm,
                                                          const int* __restrict__ atlas,
                                                          float* __restrict__ partials,
                                                          const int SPl) {
    const int tid  = threadIdx.x;
    const int wave = tid >> 6;
    const int lane = tid & 63;
    const int g    = lane >> 4;       // k-group 0..3
    const int n    = lane & 15;       // col within tile / row within roi-tile
    const int pb   = blockIdx.y * 64;
    const int chunk = blockIdx.x;

    const float4* f0 = (const float4*)(fm + (size_t)(pb +  0 + n) * NN);
    const float4* f1 = (const float4*)(fm + (size_t)(pb + 16 + n) * NN);
    const float4* f2 = (const float4*)(fm + (size_t)(pb + 32 + n) * NN);
    const float4* f3 = (const float4*)(fm + (size_t)(pb + 48 + n) * NN);
    const int4*   atlas4 = (const int4*)atlas;

    f32x4 acc[4][4];
    #pragma unroll
    for (int t = 0; t < 4; ++t)
        #pragma unroll
        for (int p = 0; p < 4; ++p)
            acc[t][p] = (f32x4){0.f, 0.f, 0.f, 0.f};

    const int t0 = wave * 4;
    const int cbase = t0 * 16 + n + 1;     // label for roi-tile t: cbase + 16t

    const int s0 = chunk * SPl;
    const int send = min(s0 + SPl, TOTFULL);

    for (int s = s0; s < send; ++s) {
        const int i4 = s * 8 + 2 * g;
        int4 la = atlas4[i4];
        int4 lb = atlas4[i4 + 1];
        float4 a0 = f0[i4], b0 = f0[i4 + 1];
        float4 a1 = f1[i4], b1 = f1[i4 + 1];
        float4 a2 = f2[i4], b2 = f2[i4 + 1];
        float4 a3 = f3[i4], b3 = f3[i4 + 1];
        bf16x8 A0 = mkA(la, lb, cbase);
        bf16x8 A1 = mkA(la, lb, cbase + 16);
        bf16x8 A2 = mkA(la, lb, cbase + 32);
        bf16x8 A3 = mkA(la, lb, cbase + 48);
        {
            bf16x8 B = mkB(a0, b0);
            acc[0][0] = __builtin_amdgcn_mfma_f32_16x16x32_bf16(A0, B, acc[0][0], 0, 0, 0);
            acc[1][0] = __builtin_amdgcn_mfma_f32_16x16x32_bf16(A1, B, acc[1][0], 0, 0, 0);
            acc[2][0] = __builtin_amdgcn_mfma_f32_16x16x32_bf16(A2, B, acc[2][0], 0, 0, 0);
            acc[3][0] = __builtin_amdgcn_mfma_f32_16x16x32_bf16(A3, B, acc[3][0], 0, 0, 0);
        }
        {
            bf16x8 B = mkB(a1, b1);
            acc[0][1] = __builtin_amdgcn_mfma_f32_16x16x32_bf16(A0, B, acc[0][1], 0, 0, 0);
            acc[1][1] = __builtin_amdgcn_mfma_f32_16x16x32_bf16(A1, B, acc[1][1], 0, 0, 0);
            acc[2][1] = __builtin_amdgcn_mfma_f32_16x16x32_bf16(A2, B, acc[2][1], 0, 0, 0);
            acc[3][1] = __builtin_amdgcn_mfma_f32_16x16x32_bf16(A3, B, acc[3][1], 0, 0, 0);
        }
        {
            bf16x8 B = mkB(a2, b2);
            acc[0][2] = __builtin_amdgcn_mfma_f32_16x16x32_bf16(A0, B, acc[0][2], 0, 0, 0);
            acc[1][2] = __builtin_amdgcn_mfma_f32_16x16x32_bf16(A1, B, acc[1][2], 0, 0, 0);
            acc[2][2] = __builtin_amdgcn_mfma_f32_16x16x32_bf16(A2, B, acc[2][2], 0, 0, 0);
            acc[3][2] = __builtin_amdgcn_mfma_f32_16x16x32_bf16(A3, B, acc[3][2], 0, 0, 0);
        }
        {
            bf16x8 B = mkB(a3, b3);
            acc[0][3] = __builtin_amdgcn_mfma_f32_16x16x32_bf16(A0, B, acc[0][3], 0, 0, 0);
            acc[1][3] = __builtin_amdgcn_mfma_f32_16x16x32_bf16(A1, B, acc[1][3], 0, 0, 0);
            acc[2][3] = __builtin_amdgcn_mfma_f32_16x16x32_bf16(A2, B, acc[2][3], 0, 0, 0);
            acc[3][3] = __builtin_amdgcn_mfma_f32_16x16x32_bf16(A3, B, acc[3][3], 0, 0, 0);
        }
    }

    // tail step (28 valid voxels): g==3's second int4/float4 is OOB
    if (s0 <= TOTFULL && TOTFULL < s0 + SPl) {
        const int i4 = TOTFULL * 8 + 2 * g;
        const int4   zi = {0, 0, 0, 0};
        const float4 zf = {0.f, 0.f, 0.f, 0.f};
        const bool ok = (i4 + 1 < NVEC);
        int4 la = atlas4[i4];
        int4 lb = ok ? atlas4[i4 + 1] : zi;
        bf16x8 A[4];
        #pragma unroll
        for (int t = 0; t < 4; ++t) A[t] = mkA(la, lb, cbase + 16 * t);
        const float4* fp[4] = {f0, f1, f2, f3};
        #pragma unroll
        for (int p = 0; p < 4; ++p) {
            float4 fa = fp[p][i4];
            float4 fb = ok ? fp[p][i4 + 1] : zf;
            bf16x8 B = mkB(fa, fb);
            #pragma unroll
            for (int t = 0; t < 4; ++t)
                acc[t][p] = __builtin_amdgcn_mfma_f32_16x16x32_bf16(A[t], B, acc[t][p], 0, 0, 0);
        }
    }

    // store: partials[chunk][roi(256)][plane(1024)]
    // D layout: col = lane&15, row = 4*(lane>>4)+i
    float* pc = partials + (size_t)chunk * (MROI * NPLANES);
    const int rbase = 4 * g;
    #pragma unroll
    for (int t = 0; t < 4; ++t)
        #pragma unroll
        for (int p = 0; p < 4; ++p)
            #pragma unroll
            for (int i = 0; i < 4; ++i)
                pc[(size_t)((t0 + t) * 16 + rbase + i) * NPLANES + (pb + 16 * p + n)] = acc[t][p][i];
}

// ---------------- finalize: reduce chunks + divide + mask ----------------
__global__ __launch_bounds__(256) void roi_final2(const float* __restrict__ partials,
                                                  const float* __restrict__ counts,
                                                  float* __restrict__ out,
                                                  const int kch) {
    const int j = blockIdx.x * 256 + threadIdx.x;
    if (j < NFEAT) {
        const int c = j & (NC - 1);
        const int r = (j >> 8) % NR;
        const int b = j / (NR * NC);
        const int plane = b * NC + c;
        float s = 0.0f;
        for (int ch = 0; ch < kch; ++ch)
            s += partials[((size_t)ch * MROI + r) * NPLANES + plane];
        const float cnt = counts[r];
        out[j] = (cnt > 0.0f) ? s / cnt : 0.0f;
    } else if (j < NFEAT + NB * NR) {
        const int r = (j - NFEAT) % NR;
        out[j] = (counts[r] > 0.0f) ? 1.0f : 0.0f;
    }
}

extern "C" void kernel_launch(void* const* d_in, const int* in_sizes, int n_in,
                              void* d_out, int out_size, void* d_ws, size_t ws_size,
                              hipStream_t stream) {
    const float* fm    = (const float*)d_in[0];
    const int*   atlas = (const int*)d_in[1];
    float*       out   = (float*)d_out;

    float* counts   = (float*)d_ws;     // 256 floats
    float* partials = counts + 256;     // kch * MROI * NPLANES floats

    int kch = 64;
    while (kch > 16 &&
           ws_size < (size_t)(256 + (size_t)kch * MROI * NPLANES) * sizeof(float))
        kch >>= 1;
    const int spl = (TOTSTEPS + kch - 1) / kch;

    hipMemsetAsync(counts, 0, NR * sizeof(float), stream);

    roi_count<<<(NVEC + 255) / 256, 256, 0, stream>>>(atlas, counts);

    roi_accum_mfma4<<<dim3(kch, NPLANES / 64), 256, 0, stream>>>(fm, atlas, partials, spl);

    const int total = NFEAT + NB * NR;
    roi_final2<<<(total + 255) / 256, 256, 0, stream>>>(partials, counts, out, kch);
}

// Round 6
// 175.664 us; speedup vs baseline: 3.8893x; 1.4130x over previous
//
#include <hip/hip_runtime.h>

#define NB 4
#define NC 256
#define ND 46
#define NH 55
#define NW 46
#define NN (ND*NH*NW)        // 116380
#define NVEC (NN/4)          // 29095
#define NR 200
#define NL 201
#define NPLANES (NB*NC)      // 1024
#define NFEAT (NB*NR*NC)     // 204800
#define MROI 256             // padded roi rows
#define CHV 64               // voxels per staged chunk (2 k-steps of 32)
#define NCHF 1818            // full chunks: 1818*64 = 116352
#define TAILF4 7             // tail float4s: voxels 116352..116379 (28)
#define LROW 36              // LDS row stride in u32 (144 B = 128 data + 16 pad)

typedef __attribute__((ext_vector_type(8))) short bf16x8;
typedef __attribute__((ext_vector_type(4))) float f32x4;

union BU { uint4 u; bf16x8 v; };

// two f32 -> packed bf16 pair (round-half-up, 2 add + 1 v_perm)
__device__ __forceinline__ unsigned pkbf(float x, float y) {
    unsigned ux = __float_as_uint(x) + 0x8000u;
    unsigned uy = __float_as_uint(y) + 0x8000u;
    return __builtin_amdgcn_perm(uy, ux, 0x07060302u);
}
// packed one-hot pair: lo match -> 0x3F80 (bf16 1.0), hi match -> 0x3F800000
__device__ __forceinline__ unsigned oh2(int l0, int l1, int c) {
    return (l0 == c ? 0x3F80u : 0u) | (l1 == c ? 0x3F800000u : 0u);
}
__device__ __forceinline__ bf16x8 mkA(const int4& la, const int4& lb, int c) {
    union { unsigned u[4]; bf16x8 v; } x;
    x.u[0] = oh2(la.x, la.y, c);
    x.u[1] = oh2(la.z, la.w, c);
    x.u[2] = oh2(lb.x, lb.y, c);
    x.u[3] = oh2(lb.z, lb.w, c);
    return x.v;
}

// ---------------- counts: histogram of atlas labels ----------------
__global__ __launch_bounds__(256) void roi_count(const int* __restrict__ atlas,
                                                 float* __restrict__ counts) {
    __shared__ float h[NL];
    const int tid = threadIdx.x;
    for (int i = tid; i < NL; i += 256) h[i] = 0.0f;
    __syncthreads();
    const int iv = blockIdx.x * 256 + tid;
    if (iv < NVEC) {
        int4 lab = ((const int4*)atlas)[iv];
        atomicAdd(&h[lab.x], 1.0f);
        atomicAdd(&h[lab.y], 1.0f);
        atomicAdd(&h[lab.z], 1.0f);
        atomicAdd(&h[lab.w], 1.0f);
    }
    __syncthreads();
    for (int i = tid; i < NL; i += 256) {
        float v = h[i];
        if (i > 0 && v != 0.0f) atomicAdd(&counts[i - 1], v);
    }
}

// ---------------- main: LDS-staged one-hot MFMA GEMM ----------------
// grid = (KCH, NPLANES/64); block = 256 (4 waves).
// Block C-tile: 256 rois x 64 planes. Wave w: rois 64w..64w+63.
// Per 64-voxel chunk: coalesced stage fm f32 -> bf16 in LDS, then
// 2 k-steps of (A one-hot build + 4x ds_read_b128 B + 16 MFMA).
__global__ __launch_bounds__(256, 4) void roi_accum_lds(const float* __restrict__ fm,
                                                        const int* __restrict__ atlas,
                                                        float* __restrict__ partials,
                                                        const int SPl) {
    __shared__ unsigned lds[64 * LROW];   // 9216 B
    const int tid  = threadIdx.x;
    const int wave = tid >> 6;
    const int lane = tid & 63;
    const int g    = lane >> 4;
    const int n    = lane & 15;
    const int pb   = blockIdx.y * 64;
    const int chunk = blockIdx.x;

    // staging role: thread t handles plane sr, 16-voxel quarter sc
    const int sr = tid >> 2;
    const int sc = tid & 3;
    const float4* sf  = (const float4*)(fm + (size_t)(pb + sr) * NN);
    unsigned*     swp = &lds[sr * LROW + sc * 8];   // 32 B slot

    const int4* atlas4 = (const int4*)atlas;

    f32x4 acc[4][4];
    #pragma unroll
    for (int t = 0; t < 4; ++t)
        #pragma unroll
        for (int p = 0; p < 4; ++p)
            acc[t][p] = (f32x4){0.f, 0.f, 0.f, 0.f};

    const int t0 = wave * 4;
    const int cbase = t0 * 16 + n + 1;

    const int c0 = chunk * SPl;
    const int c1 = min(c0 + SPl, NCHF);

    float4 L0, L1, L2, L3;
    if (c0 < c1) {
        const float4* p = sf + c0 * 16 + sc * 4;
        L0 = p[0]; L1 = p[1]; L2 = p[2]; L3 = p[3];
    }

    for (int ch = c0; ch < c1; ++ch) {
        const unsigned u0 = pkbf(L0.x, L0.y), u1 = pkbf(L0.z, L0.w);
        const unsigned u2 = pkbf(L1.x, L1.y), u3 = pkbf(L1.z, L1.w);
        const unsigned u4 = pkbf(L2.x, L2.y), u5 = pkbf(L2.z, L2.w);
        const unsigned u6 = pkbf(L3.x, L3.y), u7 = pkbf(L3.z, L3.w);
        __syncthreads();                       // prior chunk's reads done
        ((uint4*)swp)[0] = make_uint4(u0, u1, u2, u3);
        ((uint4*)(swp + 4))[0] = make_uint4(u4, u5, u6, u7);
        __syncthreads();                       // tile visible
        if (ch + 1 < c1) {                     // issue next loads early
            const float4* p = sf + (ch + 1) * 16 + sc * 4;
            L0 = p[0]; L1 = p[1]; L2 = p[2]; L3 = p[3];
        }
        #pragma unroll
        for (int ks = 0; ks < 2; ++ks) {
            const int i4 = (ch * 2 + ks) * 8 + 2 * g;
            int4 la = atlas4[i4];
            int4 lb = atlas4[i4 + 1];
            BU B0, B1, B2, B3;
            B0.u = *(const uint4*)&lds[(0 * 16 + n) * LROW + ks * 16 + g * 4];
            B1.u = *(const uint4*)&lds[(1 * 16 + n) * LROW + ks * 16 + g * 4];
            B2.u = *(const uint4*)&lds[(2 * 16 + n) * LROW + ks * 16 + g * 4];
            B3.u = *(const uint4*)&lds[(3 * 16 + n) * LROW + ks * 16 + g * 4];
            #pragma unroll
            for (int t = 0; t < 4; ++t) {
                bf16x8 A = mkA(la, lb, cbase + 16 * t);
                acc[t][0] = __builtin_amdgcn_mfma_f32_16x16x32_bf16(A, B0.v, acc[t][0], 0, 0, 0);
                acc[t][1] = __builtin_amdgcn_mfma_f32_16x16x32_bf16(A, B1.v, acc[t][1], 0, 0, 0);
                acc[t][2] = __builtin_amdgcn_mfma_f32_16x16x32_bf16(A, B2.v, acc[t][2], 0, 0, 0);
                acc[t][3] = __builtin_amdgcn_mfma_f32_16x16x32_bf16(A, B3.v, acc[t][3], 0, 0, 0);
            }
        }
    }

    // ---- tail: 28 voxels (7 float4/plane), handled by last k-chunk block ----
    if (chunk == gridDim.x - 1) {
        const float4 zf = {0.f, 0.f, 0.f, 0.f};
        unsigned u[8];
        #pragma unroll
        for (int i = 0; i < 4; ++i) {
            const int idx = sc * 4 + i;
            float4 v = (idx < TAILF4) ? sf[NCHF * 16 + idx] : zf;
            u[2 * i]     = pkbf(v.x, v.y);
            u[2 * i + 1] = pkbf(v.z, v.w);
        }
        __syncthreads();
        ((uint4*)swp)[0] = make_uint4(u[0], u[1], u[2], u[3]);
        ((uint4*)(swp + 4))[0] = make_uint4(u[4], u[5], u[6], u[7]);
        __syncthreads();
        const int i4 = NCHF * 16 + 2 * g;            // atlas float4 index
        const int4 zi = {0, 0, 0, 0};
        int4 la = atlas4[i4];
        int4 lb = (2 * g + 1 < TAILF4) ? atlas4[i4 + 1] : zi;
        BU B0, B1, B2, B3;
        B0.u = *(const uint4*)&lds[(0 * 16 + n) * LROW + g * 4];
        B1.u = *(const uint4*)&lds[(1 * 16 + n) * LROW + g * 4];
        B2.u = *(const uint4*)&lds[(2 * 16 + n) * LROW + g * 4];
        B3.u = *(const uint4*)&lds[(3 * 16 + n) * LROW + g * 4];
        #pragma unroll
        for (int t = 0; t < 4; ++t) {
            bf16x8 A = mkA(la, lb, cbase + 16 * t);
            acc[t][0] = __builtin_amdgcn_mfma_f32_16x16x32_bf16(A, B0.v, acc[t][0], 0, 0, 0);
            acc[t][1] = __builtin_amdgcn_mfma_f32_16x16x32_bf16(A, B1.v, acc[t][1], 0, 0, 0);
            acc[t][2] = __builtin_amdgcn_mfma_f32_16x16x32_bf16(A, B2.v, acc[t][2], 0, 0, 0);
            acc[t][3] = __builtin_amdgcn_mfma_f32_16x16x32_bf16(A, B3.v, acc[t][3], 0, 0, 0);
        }
    }

    // store: partials[chunk][roi(256)][plane(1024)]
    // D layout: col = lane&15, row = 4*(lane>>4)+i
    float* pc = partials + (size_t)chunk * (MROI * NPLANES);
    const int rbase = 4 * g;
    #pragma unroll
    for (int t = 0; t < 4; ++t)
        #pragma unroll
        for (int p = 0; p < 4; ++p)
            #pragma unroll
            for (int i = 0; i < 4; ++i)
                pc[(size_t)((t0 + t) * 16 + rbase + i) * NPLANES + (pb + 16 * p + n)] = acc[t][p][i];
}

// ---------------- finalize: reduce chunks + divide + mask ----------------
__global__ __launch_bounds__(256) void roi_final2(const float* __restrict__ partials,
                                                  const float* __restrict__ counts,
                                                  float* __restrict__ out,
                                                  const int kch) {
    const int j = blockIdx.x * 256 + threadIdx.x;
    if (j < NFEAT) {
        const int c = j & (NC - 1);
        const int r = (j >> 8) % NR;
        const int b = j / (NR * NC);
        const int plane = b * NC + c;
        float s = 0.0f;
        for (int ch = 0; ch < kch; ++ch)
            s += partials[((size_t)ch * MROI + r) * NPLANES + plane];
        const float cnt = counts[r];
        out[j] = (cnt > 0.0f) ? s / cnt : 0.0f;
    } else if (j < NFEAT + NB * NR) {
        const int r = (j - NFEAT) % NR;
        out[j] = (counts[r] > 0.0f) ? 1.0f : 0.0f;
    }
}

extern "C" void kernel_launch(void* const* d_in, const int* in_sizes, int n_in,
                              void* d_out, int out_size, void* d_ws, size_t ws_size,
                              hipStream_t stream) {
    const float* fm    = (const float*)d_in[0];
    const int*   atlas = (const int*)d_in[1];
    float*       out   = (float*)d_out;

    float* counts   = (float*)d_ws;     // 256 floats
    float* partials = counts + 256;     // kch * MROI * NPLANES floats

    int kch = 64;
    while (kch > 16 &&
           ws_size < (size_t)(256 + (size_t)kch * MROI * NPLANES) * sizeof(float))
        kch >>= 1;
    const int spl = (NCHF + kch - 1) / kch;

    hipMemsetAsync(counts, 0, NR * sizeof(float), stream);

    roi_count<<<(NVEC + 255) / 256, 256, 0, stream>>>(atlas, counts);

    roi_accum_lds<<<dim3(kch, NPLANES / 64), 256, 0, stream>>>(fm, atlas, partials, spl);

    const int total = NFEAT + NB * NR;
    roi_final2<<<(total + 255) / 256, 256, 0, stream>>>(partials, counts, out, kch);
}